// Round 2
// baseline (476.277 us; speedup 1.0000x reference)
//
#include <hip/hip_runtime.h>
#include <math.h>

#define NA 50000
#define NB 50000
#define EMB 35
#define EMB2 70
#define EMB3 105
#define DEG 32
#define EMBP 36      // padded new_emb row: 35 data + 1.0 (den trick); 144 B
#define XPAD 112     // padded x row (448 B)

struct TransformArgs {
    const float* srcfeat[4];  // rows that get transformed (new_emb source)
    const float* attfeat[4];  // rows for s_src (the aggregating side's features)
    const float* W[4];
    const float* b[4];
    const float* att[4];      // 70 floats: [0:35] src-att, [35:70] dst-att
    float* emb[4];            // out: [50000][EMBP]
    float* sdst[4];           // out: [50000]
    float* ssrc[4];           // out: [50000]
};

__global__ __launch_bounds__(256) void k_transform(TransformArgs A) {
    const int c = blockIdx.y;
    const int r = blockIdx.x * 256 + threadIdx.x;
    if (r >= NA) return;

    const float* __restrict__ W   = A.W[c];
    const float* __restrict__ bb  = A.b[c];
    const float* __restrict__ att = A.att[c];
    const float* __restrict__ sf  = A.srcfeat[c];

    float row[EMB];
    #pragma unroll
    for (int k = 0; k < EMB; ++k) row[k] = sf[(size_t)r * EMB + k];

    float out[EMB];
    #pragma unroll
    for (int j = 0; j < EMB; ++j) out[j] = bb[j];

    for (int k = 0; k < EMB; ++k) {       // W[k*EMB+j] is wave-uniform -> s_load
        const float rk = row[k];
        #pragma unroll
        for (int j = 0; j < EMB; ++j) out[j] = fmaf(rk, W[k * EMB + j], out[j]);
    }

    float* __restrict__ emb = A.emb[c];
    float sd = 0.0f;
    #pragma unroll
    for (int j = 0; j < EMB; ++j) {
        sd = fmaf(out[j], att[EMB + j], sd);
        emb[(size_t)r * EMBP + j] = out[j];
    }
    emb[(size_t)r * EMBP + EMB] = 1.0f;   // den trick: 36th element = 1.0
    A.sdst[c][r] = sd;

    const float* __restrict__ af = A.attfeat[c];
    float ss = 0.0f;
    #pragma unroll
    for (int k = 0; k < EMB; ++k) ss = fmaf(af[(size_t)r * EMB + k], att[k], ss);
    A.ssrc[c][r] = ss;
}

struct AggArgs {
    const int* dst[4];
    const float* emb[4];
    const float* sdst[4];
    const float* ssrc[4];
    const float* feat[2];   // feature_a, feature_b
    float* x[2];            // x_a, x_b  ([N][XPAD])
};

// One wave per node; lanes 0..31 own group-0 edges, lanes 32..63 group-1.
// Broadcast (w, d) per edge via readlane (SGPR) -> uniform-base coalesced
// row gathers, no DS ops. den accumulated as the 36th row element.
__global__ __launch_bounds__(256) void k_agg(AggArgs A) {
    const int lane = threadIdx.x & 63;
    const int wid  = threadIdx.x >> 6;
    const int side = blockIdx.y;
    const int node = blockIdx.x * 4 + wid;   // 12500 blocks * 4 waves = 50000
    const int g    = lane >> 5;
    const int c0   = side * 2, c1 = c0 + 1;

    const int*   __restrict__ dstp  = (g == 0) ? A.dst[c0]  : A.dst[c1];
    const float* __restrict__ ssrcp = (g == 0) ? A.ssrc[c0] : A.ssrc[c1];
    const float* __restrict__ sdstp = (g == 0) ? A.sdst[c0] : A.sdst[c1];

    const int e = node * DEG + (lane & 31);
    const int d = dstp[e];
    const float z = ssrcp[node] + sdstp[d];
    const float t = (z > 0.0f) ? z : 0.1f * expm1f(z);
    const float w = expf(t);

    const float* __restrict__ emb0 = A.emb[c0];
    const float* __restrict__ emb1 = A.emb[c1];

    float acc0 = 0.0f, acc1 = 0.0f;
    #pragma unroll
    for (int e2 = 0; e2 < DEG; ++e2) {
        const float w0 = __uint_as_float(__builtin_amdgcn_readlane(__float_as_uint(w), e2));
        const int   d0 = __builtin_amdgcn_readlane(d, e2);
        const float w1 = __uint_as_float(__builtin_amdgcn_readlane(__float_as_uint(w), 32 + e2));
        const int   d1 = __builtin_amdgcn_readlane(d, 32 + e2);
        if (lane < EMBP) {   // 36 lanes: 35 data + den slot
            acc0 = fmaf(w0, emb0[(size_t)d0 * EMBP + lane], acc0);
            acc1 = fmaf(w1, emb1[(size_t)d1 * EMBP + lane], acc1);
        }
    }
    const float den0 = __uint_as_float(__builtin_amdgcn_readlane(__float_as_uint(acc0), EMB));
    const float den1 = __uint_as_float(__builtin_amdgcn_readlane(__float_as_uint(acc1), EMB));

    float* __restrict__ xrow = A.x[side] + (size_t)node * XPAD;
    const float* __restrict__ feat = A.feat[side];
    if (lane < EMB) {
        xrow[lane]           = feat[(size_t)node * EMB + lane];
        xrow[EMB + lane]     = acc0 / den0;
        xrow[2 * EMB + lane] = acc1 / den1;
    }
}

__global__ __launch_bounds__(256) void k_mlp(
        const float* __restrict__ x,          // [NA+NB][XPAD] contiguous
        const float* __restrict__ W1, const float* __restrict__ b1,
        const float* __restrict__ alpha_p,
        const float* __restrict__ W2, const float* __restrict__ b2,
        float* __restrict__ out) {
    const int i = blockIdx.x * 256 + threadIdx.x;
    if (i >= NA + NB) return;
    const float* __restrict__ xrow = x + (size_t)i * XPAD;

    float h[EMB2];
    #pragma unroll
    for (int j = 0; j < EMB2; ++j) h[j] = b1[j];

    #pragma unroll 7
    for (int k = 0; k < EMB3; ++k) {      // W1[k*70+j] wave-uniform -> s_load
        const float xk = xrow[k];
        #pragma unroll
        for (int j = 0; j < EMB2; ++j) h[j] = fmaf(xk, W1[k * EMB2 + j], h[j]);
    }

    const float alpha = alpha_p[0];
    float o[EMB];
    #pragma unroll
    for (int m = 0; m < EMB; ++m) o[m] = b2[m];

    for (int j = 0; j < EMB2; ++j) {
        float hj = h[j];
        hj = (hj > 0.0f) ? hj : alpha * hj;
        #pragma unroll
        for (int m = 0; m < EMB; ++m) o[m] = fmaf(hj, W2[j * EMB + m], o[m]);
    }

    float* __restrict__ orow = out + (size_t)i * EMB;
    #pragma unroll
    for (int m = 0; m < EMB; ++m) orow[m] = o[m];
}

extern "C" void kernel_launch(void* const* d_in, const int* in_sizes, int n_in,
                              void* d_out, int out_size, void* d_ws, size_t ws_size,
                              hipStream_t stream) {
    const float* feature_a = (const float*)d_in[0];
    const float* feature_b = (const float*)d_in[1];
    const int* dst_ab_pos  = (const int*)d_in[2];
    const int* dst_ab_neg  = (const int*)d_in[3];
    const int* dst_ba_pos  = (const int*)d_in[4];
    const int* dst_ba_neg  = (const int*)d_in[5];
    // per-config params: abp, abn, bap, ban
    const float* Wc[4]  = {(const float*)d_in[6],  (const float*)d_in[9],
                           (const float*)d_in[12], (const float*)d_in[15]};
    const float* bc[4]  = {(const float*)d_in[7],  (const float*)d_in[10],
                           (const float*)d_in[13], (const float*)d_in[16]};
    const float* attc[4]= {(const float*)d_in[8],  (const float*)d_in[11],
                           (const float*)d_in[14], (const float*)d_in[17]};
    const float* W1 = (const float*)d_in[18];
    const float* b1 = (const float*)d_in[19];
    const float* alpha = (const float*)d_in[20];
    const float* W2 = (const float*)d_in[21];
    const float* b2 = (const float*)d_in[22];

    float* ws = (float*)d_ws;
    // workspace layout (floats)
    float* emb[4], *sdst[4], *ssrc[4];
    size_t off = 0;
    for (int c = 0; c < 4; ++c) { emb[c] = ws + off; off += (size_t)NA * EMBP; }
    for (int c = 0; c < 4; ++c) { sdst[c] = ws + off; off += NA; }
    for (int c = 0; c < 4; ++c) { ssrc[c] = ws + off; off += NA; }
    float* xa = ws + off; off += (size_t)NA * XPAD;   // xa, xb contiguous
    float* xb = ws + off; off += (size_t)NB * XPAD;

    TransformArgs ta;
    // new_emb source: ab* transform feature_b, ba* transform feature_a
    ta.srcfeat[0] = feature_b; ta.srcfeat[1] = feature_b;
    ta.srcfeat[2] = feature_a; ta.srcfeat[3] = feature_a;
    // s_src side: ab* score feature_a, ba* score feature_b
    ta.attfeat[0] = feature_a; ta.attfeat[1] = feature_a;
    ta.attfeat[2] = feature_b; ta.attfeat[3] = feature_b;
    for (int c = 0; c < 4; ++c) {
        ta.W[c] = Wc[c]; ta.b[c] = bc[c]; ta.att[c] = attc[c];
        ta.emb[c] = emb[c]; ta.sdst[c] = sdst[c]; ta.ssrc[c] = ssrc[c];
    }
    dim3 g1((NA + 255) / 256, 4);
    k_transform<<<g1, 256, 0, stream>>>(ta);

    AggArgs aa;
    aa.dst[0] = dst_ab_pos; aa.dst[1] = dst_ab_neg;
    aa.dst[2] = dst_ba_pos; aa.dst[3] = dst_ba_neg;
    for (int c = 0; c < 4; ++c) {
        aa.emb[c] = emb[c]; aa.sdst[c] = sdst[c]; aa.ssrc[c] = ssrc[c];
    }
    aa.feat[0] = feature_a; aa.feat[1] = feature_b;
    aa.x[0] = xa; aa.x[1] = xb;
    dim3 g2(NA / 4, 2);   // 4 waves (nodes) per block
    k_agg<<<g2, 256, 0, stream>>>(aa);

    k_mlp<<<(NA + NB + 255) / 256, 256, 0, stream>>>(xa, W1, b1, alpha, W2, b2,
                                                     (float*)d_out);
}

// Round 3
// 453.468 us; speedup vs baseline: 1.0503x; 1.0503x over previous
//
#include <hip/hip_runtime.h>
#include <hip/hip_fp16.h>
#include <math.h>

#define NA 50000
#define NB 50000
#define NT (NA + NB)
#define EMB 35
#define EMB2 70
#define EMB3 105
#define DEG 32
#define EH 36      // fp16 emb row: 35 data + den slot (=1.0); 72 B
#define MROW 72    // mbuf row: mp[36] + mn[36] (slots 35/71 are den junk)

// ---------------------------------------------------------------- transform
struct TArgs {
    const float* fa; const float* fb;
    const float* W[4]; const float* b[4]; const float* att[4];
    __half* embh[4]; float* sdst[4]; float* ssrc[4];
};

__global__ __launch_bounds__(128) void k_transform(TArgs A) {
    __shared__ float sfa[128 * 37];
    __shared__ float sfb[128 * 37];
    const int t = threadIdx.x;
    const int base = blockIdx.x * 128;

    // coalesced stage of both feature tiles (pad stride 37 -> no bank conflict)
    for (int it = 0; it < EMB; ++it) {
        int flat = it * 128 + t;
        int r = flat / EMB, c = flat % EMB;
        int node = base + r;
        if (node < NA) {
            sfa[r * 37 + c] = A.fa[(size_t)node * EMB + c];
            sfb[r * 37 + c] = A.fb[(size_t)node * EMB + c];
        }
    }
    __syncthreads();

    const int node = base + t;
    if (node >= NA) return;   // no further barriers

    for (int cfg = 0; cfg < 4; ++cfg) {
        const float* __restrict__ W   = A.W[cfg];
        const float* __restrict__ bb  = A.b[cfg];
        const float* __restrict__ att = A.att[cfg];
        const float* __restrict__ srow = (cfg < 2) ? (sfb + t * 37) : (sfa + t * 37);
        const float* __restrict__ arow = (cfg < 2) ? (sfa + t * 37) : (sfb + t * 37);

        float out[EMB];
        #pragma unroll
        for (int j = 0; j < EMB; ++j) out[j] = bb[j];
        for (int k = 0; k < EMB; ++k) {          // W wave-uniform -> s_load
            const float rk = srow[k];
            #pragma unroll
            for (int j = 0; j < EMB; ++j) out[j] = fmaf(rk, W[k * EMB + j], out[j]);
        }

        float sd = 0.0f, ss = 0.0f;
        #pragma unroll
        for (int j = 0; j < EMB; ++j) sd = fmaf(out[j], att[EMB + j], sd);
        #pragma unroll
        for (int k = 0; k < EMB; ++k) ss = fmaf(arow[k], att[k], ss);

        __half2* er = (__half2*)(A.embh[cfg] + (size_t)node * EH);
        #pragma unroll
        for (int jj = 0; jj < 17; ++jj)
            er[jj] = __floats2half2_rn(out[2 * jj], out[2 * jj + 1]);
        er[17] = __floats2half2_rn(out[34], 1.0f);   // den slot

        A.sdst[cfg][node] = sd;
        A.ssrc[cfg][node] = ss;
    }
}

// ---------------------------------------------------------------- aggregate
struct GArgs {
    const int* dst[4];
    const __half* embh[4];
    const float* sdst[4]; const float* ssrc[4];
    float* mbuf;   // [NT][MROW], B-side nodes at offset NA
};

// One wave = 2 nodes of ONE config. Blocks config-major -> per-XCD L2 holds
// one 3.6 MB fp16 table. Gathers batched 8-deep; no DS ops; no exec masking
// in the hot loop (lanes 18..31 / 50..63 clamp-dup the last half2).
__global__ __launch_bounds__(256) void k_agg(GArgs A) {
    const int lane = threadIdx.x & 63;
    const int wid  = __builtin_amdgcn_readfirstlane(threadIdx.x >> 6);
    const int cfg  = blockIdx.x / 6250;
    const int pair = (blockIdx.x % 6250) * 4 + wid;
    const int n0 = pair * 2, n1 = n0 + 1;
    const bool lo = (lane < 32);
    const int side = cfg >> 1;
    const int goff = (cfg & 1) * EH;
    const int li = ((lane & 31) < 17) ? (lane & 31) : 17;

    const int*   __restrict__ dst  = A.dst[cfg];
    const float* __restrict__ sds  = A.sdst[cfg];
    const __half* __restrict__ eh  = A.embh[cfg];

    const int d = dst[(size_t)pair * 64 + lane];   // 64-lane coalesced
    const float s0 = A.ssrc[cfg][n0];
    const float s1 = A.ssrc[cfg][n1];
    const float z = (lo ? s0 : s1) + sds[d];
    const float tt = (z > 0.0f) ? z : 0.1f * expm1f(z);
    const float w = expf(tt);

    float accx = 0.0f, accy = 0.0f;
    #pragma unroll
    for (int e0 = 0; e0 < DEG; e0 += 8) {
        __half2 hv[8];
        #pragma unroll
        for (int i = 0; i < 8; ++i) {
            const int d0 = __builtin_amdgcn_readlane(d, e0 + i);
            const int d1 = __builtin_amdgcn_readlane(d, 32 + e0 + i);
            const int dd = lo ? d0 : d1;
            hv[i] = *((const __half2*)(eh + (size_t)dd * EH) + li);
        }
        #pragma unroll
        for (int i = 0; i < 8; ++i) {
            const float w0 = __uint_as_float(__builtin_amdgcn_readlane(__float_as_uint(w), e0 + i));
            const float w1 = __uint_as_float(__builtin_amdgcn_readlane(__float_as_uint(w), 32 + e0 + i));
            const float fw = lo ? w0 : w1;
            const float2 f = __half22float2(hv[i]);
            accx = fmaf(fw, f.x, accx);
            accy = fmaf(fw, f.y, accy);
        }
    }

    // den = sum(w) accumulated in elem 35 (lane 17 .y / lane 49 .y)
    const float den0 = __uint_as_float(__builtin_amdgcn_readlane(__float_as_uint(accy), 17));
    const float den1 = __uint_as_float(__builtin_amdgcn_readlane(__float_as_uint(accy), 49));
    const float den = lo ? den0 : den1;

    if ((lane & 31) < 18) {
        const int node = side * NA + (lo ? n0 : n1);
        float2 m2;
        m2.x = accx / den;
        m2.y = accy / den;
        *(float2*)(A.mbuf + (size_t)node * MROW + goff + 2 * li) = m2;
    }
}

// ---------------------------------------------------------------- MLP
__global__ __launch_bounds__(128) void k_mlp(
        const float* __restrict__ fa, const float* __restrict__ fb,
        const float* __restrict__ mbuf,
        const float* __restrict__ W1, const float* __restrict__ b1,
        const float* __restrict__ alpha_p,
        const float* __restrict__ W2, const float* __restrict__ b2,
        float* __restrict__ out) {
    __shared__ float sx[128 * 37];   // feat tile; reused as out tile
    __shared__ float sm[128 * 73];   // m tile (stride 73: conflict-free)
    const int t = threadIdx.x;
    const int base = blockIdx.x * 128;

    for (int it = 0; it < EMB; ++it) {
        int flat = it * 128 + t;
        int r = flat / EMB, c = flat % EMB;
        int node = base + r;
        if (node < NT)
            sx[r * 37 + c] = (node < NA) ? fa[(size_t)node * EMB + c]
                                         : fb[(size_t)(node - NA) * EMB + c];
    }
    for (int it = 0; it < MROW; ++it) {
        int flat = it * 128 + t;
        int r = flat / MROW, j = flat % MROW;
        int node = base + r;
        if (node < NT) sm[r * 73 + j] = mbuf[(size_t)node * MROW + j];
    }
    __syncthreads();

    const int node = base + t;
    float o[EMB];
    if (node < NT) {
        float h[EMB2];
        #pragma unroll
        for (int j = 0; j < EMB2; ++j) h[j] = b1[j];

        for (int k = 0; k < EMB; ++k) {                 // feat part
            const float xk = sx[t * 37 + k];
            #pragma unroll
            for (int j = 0; j < EMB2; ++j) h[j] = fmaf(xk, W1[k * EMB2 + j], h[j]);
        }
        for (int j2 = 0; j2 < EMB2; ++j2) {             // m part (skip den slots)
            const float xk = sm[t * 73 + j2 + (j2 >= EMB ? 1 : 0)];
            #pragma unroll
            for (int j = 0; j < EMB2; ++j) h[j] = fmaf(xk, W1[(EMB + j2) * EMB2 + j], h[j]);
        }

        const float alpha = alpha_p[0];
        #pragma unroll
        for (int m = 0; m < EMB; ++m) o[m] = b2[m];
        for (int j = 0; j < EMB2; ++j) {
            float hj = h[j];
            hj = (hj > 0.0f) ? hj : alpha * hj;
            #pragma unroll
            for (int m = 0; m < EMB; ++m) o[m] = fmaf(hj, W2[j * EMB + m], o[m]);
        }
    }
    __syncthreads();            // everyone done reading sx
    if (node < NT) {
        #pragma unroll
        for (int m = 0; m < EMB; ++m) sx[t * 37 + m] = o[m];
    }
    __syncthreads();
    for (int it = 0; it < EMB; ++it) {
        int flat = it * 128 + t;
        int r = flat / EMB, c = flat % EMB;
        int node2 = base + r;
        if (node2 < NT) out[(size_t)node2 * EMB + c] = sx[r * 37 + c];
    }
}

// ---------------------------------------------------------------- launch
extern "C" void kernel_launch(void* const* d_in, const int* in_sizes, int n_in,
                              void* d_out, int out_size, void* d_ws, size_t ws_size,
                              hipStream_t stream) {
    const float* feature_a = (const float*)d_in[0];
    const float* feature_b = (const float*)d_in[1];
    const int* dsts[4] = {(const int*)d_in[2], (const int*)d_in[3],
                          (const int*)d_in[4], (const int*)d_in[5]};
    const float* Wc[4]  = {(const float*)d_in[6],  (const float*)d_in[9],
                           (const float*)d_in[12], (const float*)d_in[15]};
    const float* bc[4]  = {(const float*)d_in[7],  (const float*)d_in[10],
                           (const float*)d_in[13], (const float*)d_in[16]};
    const float* attc[4]= {(const float*)d_in[8],  (const float*)d_in[11],
                           (const float*)d_in[14], (const float*)d_in[17]};
    const float* W1 = (const float*)d_in[18];
    const float* b1 = (const float*)d_in[19];
    const float* alpha = (const float*)d_in[20];
    const float* W2 = (const float*)d_in[21];
    const float* b2 = (const float*)d_in[22];

    char* ws = (char*)d_ws;
    size_t off = 0;
    auto carve = [&](size_t bytes) {
        char* p = ws + off;
        off += (bytes + 255) & ~(size_t)255;
        return p;
    };
    __half* embh[4]; float* sdst[4]; float* ssrc[4];
    for (int c = 0; c < 4; ++c) embh[c] = (__half*)carve((size_t)NA * EH * 2);
    for (int c = 0; c < 4; ++c) sdst[c] = (float*)carve((size_t)NA * 4);
    for (int c = 0; c < 4; ++c) ssrc[c] = (float*)carve((size_t)NA * 4);
    float* mbuf = (float*)carve((size_t)NT * MROW * 4);

    TArgs ta;
    ta.fa = feature_a; ta.fb = feature_b;
    for (int c = 0; c < 4; ++c) {
        ta.W[c] = Wc[c]; ta.b[c] = bc[c]; ta.att[c] = attc[c];
        ta.embh[c] = embh[c]; ta.sdst[c] = sdst[c]; ta.ssrc[c] = ssrc[c];
    }
    k_transform<<<(NA + 127) / 128, 128, 0, stream>>>(ta);

    GArgs ga;
    for (int c = 0; c < 4; ++c) {
        ga.dst[c] = dsts[c]; ga.embh[c] = embh[c];
        ga.sdst[c] = sdst[c]; ga.ssrc[c] = ssrc[c];
    }
    ga.mbuf = mbuf;
    k_agg<<<25000, 256, 0, stream>>>(ga);   // cfg = blockIdx.x / 6250 (config-major)

    k_mlp<<<(NT + 127) / 128, 128, 0, stream>>>(feature_a, feature_b, mbuf,
                                                W1, b1, alpha, W2, b2,
                                                (float*)d_out);
}

// Round 4
// 424.711 us; speedup vs baseline: 1.1214x; 1.0677x over previous
//
#include <hip/hip_runtime.h>
#include <hip/hip_fp16.h>
#include <math.h>

#define NA 50000
#define NB 50000
#define NT (NA + NB)
#define EMB 35
#define EMB2 70
#define EMB3 105
#define DEG 32
#define EH 36      // fp16 emb row: 35 data + den slot (=1.0); 72 B (8B-aligned)
#define MROW 72    // mbuf row: mp[36] + mn[36] floats; 288 B (16B-aligned)

// ---------------------------------------------------------------- transform
struct TArgs {
    const float* fa; const float* fb;
    const float* W[4]; const float* b[4]; const float* att[4];
    __half* embh[4]; float* sdst[4]; float* ssrc[4];
};

// blockIdx.y = cfg. Thread-per-node, streamed reads, W via wave-uniform s_load.
__global__ __launch_bounds__(256) void k_transform(TArgs A) {
    const int cfg  = blockIdx.y;
    const int node = blockIdx.x * 256 + threadIdx.x;
    if (node >= NA) return;

    const float* __restrict__ W   = A.W[cfg];
    const float* __restrict__ bb  = A.b[cfg];
    const float* __restrict__ att = A.att[cfg];
    const float* __restrict__ srcf = (cfg < 2) ? A.fb : A.fa;  // gets transformed
    const float* __restrict__ attf = (cfg < 2) ? A.fa : A.fb;  // scores s_src

    float out[EMB];
    #pragma unroll
    for (int j = 0; j < EMB; ++j) out[j] = bb[j];

    const float* __restrict__ srow = srcf + (size_t)node * EMB;
    for (int k = 0; k < EMB; ++k) {
        const float xk = srow[k];
        #pragma unroll
        for (int j = 0; j < EMB; ++j) out[j] = fmaf(xk, W[k * EMB + j], out[j]);
    }

    float sd = 0.0f;
    #pragma unroll
    for (int j = 0; j < EMB; ++j) sd = fmaf(out[j], att[EMB + j], sd);

    const float* __restrict__ arow = attf + (size_t)node * EMB;
    float ss = 0.0f;
    for (int k = 0; k < EMB; ++k) ss = fmaf(arow[k], att[k], ss);

    __half2* er = (__half2*)(A.embh[cfg] + (size_t)node * EH);
    #pragma unroll
    for (int jj = 0; jj < 17; ++jj)
        er[jj] = __floats2half2_rn(out[2 * jj], out[2 * jj + 1]);
    er[17] = __floats2half2_rn(out[34], 1.0f);   // den slot = 1.0 exact in fp16

    A.sdst[cfg][node] = sd;
    A.ssrc[cfg][node] = ss;
}

// ---------------------------------------------------------------- aggregate
struct GArgs {
    const int* dst[4];
    const __half* embh[4];
    const float* sdst[4]; const float* ssrc[4];
    float* mbuf;   // [NT][MROW], B-side nodes at offset NA
};

// One wave = 2 nodes of ONE config (lanes 0..31 / 32..63). Blocks config-major
// -> per-XCD L2 holds one 3.6 MB fp16 table. Row gathers as float2 (4 halves,
// 9 lanes/row); broadcasts via readlane (SGPR); den in row slot 35.
__global__ __launch_bounds__(256) void k_agg(GArgs A) {
    const int lane = threadIdx.x & 63;
    const int wid  = __builtin_amdgcn_readfirstlane(threadIdx.x >> 6);
    const int cfg  = blockIdx.x / 6250;
    const int pair = (blockIdx.x % 6250) * 4 + wid;
    const int n0 = pair * 2, n1 = n0 + 1;
    const bool lo = (lane < 32);
    const int side = cfg >> 1;
    const int goff = (cfg & 1) * EH;
    const int li2 = ((lane & 31) < 9) ? (lane & 31) : 8;   // float2 slot 0..8

    const int*   __restrict__ dst = A.dst[cfg];
    const float* __restrict__ sds = A.sdst[cfg];
    const __half* __restrict__ eh = A.embh[cfg];

    const int d = dst[(size_t)pair * 64 + lane];   // 64-lane coalesced
    const float s0 = A.ssrc[cfg][n0];
    const float s1 = A.ssrc[cfg][n1];
    const float z = (lo ? s0 : s1) + sds[d];
    const float tt = (z > 0.0f) ? z : 0.1f * expm1f(z);
    const float w = expf(tt);

    float a0 = 0.0f, a1 = 0.0f, a2 = 0.0f, a3 = 0.0f;
    #pragma unroll
    for (int e0 = 0; e0 < DEG; e0 += 8) {
        float2 hv[8];
        #pragma unroll
        for (int i = 0; i < 8; ++i) {
            const int dd0 = __builtin_amdgcn_readlane(d, e0 + i);
            const int dd1 = __builtin_amdgcn_readlane(d, 32 + e0 + i);
            const int dd = lo ? dd0 : dd1;
            hv[i] = ((const float2*)(eh + (size_t)dd * EH))[li2];
        }
        #pragma unroll
        for (int i = 0; i < 8; ++i) {
            const float w0 = __uint_as_float(__builtin_amdgcn_readlane(__float_as_uint(w), e0 + i));
            const float w1 = __uint_as_float(__builtin_amdgcn_readlane(__float_as_uint(w), 32 + e0 + i));
            const float fw = lo ? w0 : w1;
            const __half2* hp = (const __half2*)&hv[i];
            const float2 f0 = __half22float2(hp[0]);
            const float2 f1 = __half22float2(hp[1]);
            a0 = fmaf(fw, f0.x, a0);
            a1 = fmaf(fw, f0.y, a1);
            a2 = fmaf(fw, f1.x, a2);
            a3 = fmaf(fw, f1.y, a3);
        }
    }

    // den = sum(w): elem 35 = lane 8 (lo) / lane 40 (hi), component a3
    const float den0 = __uint_as_float(__builtin_amdgcn_readlane(__float_as_uint(a3), 8));
    const float den1 = __uint_as_float(__builtin_amdgcn_readlane(__float_as_uint(a3), 40));
    const float rden = 1.0f / (lo ? den0 : den1);

    if ((lane & 31) < 9) {
        const int node = side * NA + (lo ? n0 : n1);
        float4 m4;
        m4.x = a0 * rden; m4.y = a1 * rden; m4.z = a2 * rden; m4.w = a3 * rden;
        *(float4*)(A.mbuf + (size_t)node * MROW + goff + 4 * li2) = m4;
    }
}

// ---------------------------------------------------------------- MLP
// Thread-per-node, no LDS. Hidden layer tiled 2x35 (x streamed twice) to keep
// peak regs ~100 -> 4 waves/SIMD. W1/W2 wave-uniform -> s_load.
__global__ __launch_bounds__(256, 4) void k_mlp(
        const float* __restrict__ fa, const float* __restrict__ fb,
        const float* __restrict__ mbuf,
        const float* __restrict__ W1, const float* __restrict__ b1,
        const float* __restrict__ alpha_p,
        const float* __restrict__ W2, const float* __restrict__ b2,
        float* __restrict__ out) {
    const int node = blockIdx.x * 256 + threadIdx.x;
    if (node >= NT) return;

    const float* __restrict__ frow =
        (node < NA) ? (fa + (size_t)node * EMB) : (fb + (size_t)(node - NA) * EMB);
    const float* __restrict__ mrow = mbuf + (size_t)node * MROW;
    const float alpha = alpha_p[0];

    float o[EMB];
    #pragma unroll
    for (int m = 0; m < EMB; ++m) o[m] = b2[m];

    #pragma unroll 1
    for (int jt = 0; jt < 2; ++jt) {
        const int jo = jt * 35;
        float h[35];
        #pragma unroll
        for (int j = 0; j < 35; ++j) h[j] = b1[jo + j];

        // feat part: k = 0..34
        for (int k = 0; k < EMB; ++k) {
            const float xk = frow[k];
            #pragma unroll
            for (int j = 0; j < 35; ++j) h[j] = fmaf(xk, W1[k * EMB2 + jo + j], h[j]);
        }
        // m part: mbuf elems 0..34 -> k=35+e ; elems 36..70 -> k=34+e (skip 35,71)
        #pragma unroll 3
        for (int q = 0; q < 18; ++q) {
            const float4 v = ((const float4*)mrow)[q];
            const float c[4] = {v.x, v.y, v.z, v.w};
            #pragma unroll
            for (int ci = 0; ci < 4; ++ci) {
                const int e = q * 4 + ci;
                if (e == 35 || e == 71) continue;
                const int k = (e < 35) ? (35 + e) : (34 + e);
                const float xk = c[ci];
                #pragma unroll
                for (int j = 0; j < 35; ++j) h[j] = fmaf(xk, W1[k * EMB2 + jo + j], h[j]);
            }
        }
        // consume tile into o
        for (int j = 0; j < 35; ++j) {
            float hj = h[j];
            hj = (hj > 0.0f) ? hj : alpha * hj;
            #pragma unroll
            for (int m = 0; m < EMB; ++m) o[m] = fmaf(hj, W2[(jo + j) * EMB + m], o[m]);
        }
    }

    float* __restrict__ orow = out + (size_t)node * EMB;
    #pragma unroll
    for (int m = 0; m < EMB; ++m) orow[m] = o[m];
}

// ---------------------------------------------------------------- launch
extern "C" void kernel_launch(void* const* d_in, const int* in_sizes, int n_in,
                              void* d_out, int out_size, void* d_ws, size_t ws_size,
                              hipStream_t stream) {
    const float* feature_a = (const float*)d_in[0];
    const float* feature_b = (const float*)d_in[1];
    const int* dsts[4] = {(const int*)d_in[2], (const int*)d_in[3],
                          (const int*)d_in[4], (const int*)d_in[5]};
    const float* Wc[4]  = {(const float*)d_in[6],  (const float*)d_in[9],
                           (const float*)d_in[12], (const float*)d_in[15]};
    const float* bc[4]  = {(const float*)d_in[7],  (const float*)d_in[10],
                           (const float*)d_in[13], (const float*)d_in[16]};
    const float* attc[4]= {(const float*)d_in[8],  (const float*)d_in[11],
                           (const float*)d_in[14], (const float*)d_in[17]};
    const float* W1 = (const float*)d_in[18];
    const float* b1 = (const float*)d_in[19];
    const float* alpha = (const float*)d_in[20];
    const float* W2 = (const float*)d_in[21];
    const float* b2 = (const float*)d_in[22];

    char* ws = (char*)d_ws;
    size_t off = 0;
    auto carve = [&](size_t bytes) {
        char* p = ws + off;
        off += (bytes + 255) & ~(size_t)255;
        return p;
    };
    __half* embh[4]; float* sdst[4]; float* ssrc[4];
    for (int c = 0; c < 4; ++c) embh[c] = (__half*)carve((size_t)NA * EH * 2);
    for (int c = 0; c < 4; ++c) sdst[c] = (float*)carve((size_t)NA * 4);
    for (int c = 0; c < 4; ++c) ssrc[c] = (float*)carve((size_t)NA * 4);
    float* mbuf = (float*)carve((size_t)NT * MROW * 4);

    TArgs ta;
    ta.fa = feature_a; ta.fb = feature_b;
    for (int c = 0; c < 4; ++c) {
        ta.W[c] = Wc[c]; ta.b[c] = bc[c]; ta.att[c] = attc[c];
        ta.embh[c] = embh[c]; ta.sdst[c] = sdst[c]; ta.ssrc[c] = ssrc[c];
    }
    dim3 g1((NA + 255) / 256, 4);
    k_transform<<<g1, 256, 0, stream>>>(ta);

    GArgs ga;
    for (int c = 0; c < 4; ++c) {
        ga.dst[c] = dsts[c]; ga.embh[c] = embh[c];
        ga.sdst[c] = sdst[c]; ga.ssrc[c] = ssrc[c];
    }
    ga.mbuf = mbuf;
    k_agg<<<25000, 256, 0, stream>>>(ga);   // cfg = blockIdx.x / 6250 (config-major)

    k_mlp<<<(NT + 255) / 256, 256, 0, stream>>>(feature_a, feature_b, mbuf,
                                                W1, b1, alpha, W2, b2,
                                                (float*)d_out);
}